// Round 1
// baseline (82.573 us; speedup 1.0000x reference)
//
#include <hip/hip_runtime.h>
#include <math.h>

#define BATCH   64
#define IN_DIM  8192
#define OUT_DIM 2048
#define BRANCH  4
#define CHUNK   2048   // IN_DIM / BRANCH

__device__ __forceinline__ float sigmoidf_(float x) {
    return 1.0f / (1.0f + expf(-x));
}

// Kernel A: block-diagonal GEMM.
//   Y[(n*BRANCH + j)*OUT_DIM + o] = sum_c W[o*4+j][j*CHUNK+c] * X[n][j*CHUNK+c]
// Tile: 64 batches x 32 outputs, one branch per block. Grid = 64 o-tiles * 4 branches = 256 blocks.
// K-tile 64 with register prefetch (single LDS buffer).
__global__ __launch_bounds__(256) void dend_gemm(const float* __restrict__ X,
                                                 const float* __restrict__ W,
                                                 float* __restrict__ Y) {
    // transposed staging: pad 66/38 -> 4-way write conflicts (vs 8/32-way), float2-aligned reads
    __shared__ float Xs[64][66];
    __shared__ float Ws[64][38];
    __shared__ float Ys[32][65];

    const int t   = threadIdx.x;
    const int bid = blockIdx.x;
    const int j   = bid & 3;
    const int o0  = (bid >> 2) << 5;   // *32
    const int jb  = j * CHUNK;

    // staging coords: lane-minor along k (coalesced global reads)
    const int kk = t & 63;
    const int q  = t >> 6;             // 0..3

    // compute coords: 16 n-groups x 16 o-groups
    const int ng  = t & 15;
    const int og  = t >> 4;
    const int n0  = ng << 2;           // 4 batches
    const int oo0 = og << 1;           // 2 outputs

    const float* Xp = X + jb + kk;
    const float* Wp = W + (size_t)(o0 * 4 + j) * IN_DIM + jb + kk;

    float acc[4][2];
#pragma unroll
    for (int a = 0; a < 4; ++a) { acc[a][0] = 0.0f; acc[a][1] = 0.0f; }

    float xr[16];
    float wr[8];

    // prologue: load tile 0 into registers
#pragma unroll
    for (int i = 0; i < 16; ++i)
        xr[i] = Xp[(size_t)((q << 4) + i) * IN_DIM];
#pragma unroll
    for (int i = 0; i < 8; ++i)
        wr[i] = Wp[(size_t)(((q << 3) + i) << 2) * IN_DIM];

    for (int kt = 0; kt < CHUNK / 64; ++kt) {
        if (kt) __syncthreads();           // previous compute done -> LDS free
        // registers -> LDS (transposed)
#pragma unroll
        for (int i = 0; i < 16; ++i)
            Xs[kk][(q << 4) + i] = xr[i];
#pragma unroll
        for (int i = 0; i < 8; ++i)
            Ws[kk][(q << 3) + i] = wr[i];
        __syncthreads();

        // prefetch next tile (overlaps with compute below)
        if (kt + 1 < CHUNK / 64) {
            const int k1 = (kt + 1) << 6;
#pragma unroll
            for (int i = 0; i < 16; ++i)
                xr[i] = Xp[(size_t)((q << 4) + i) * IN_DIM + k1];
#pragma unroll
            for (int i = 0; i < 8; ++i)
                wr[i] = Wp[(size_t)(((q << 3) + i) << 2) * IN_DIM + k1];
        }

        // compute: 64 k-steps x 8 FMA
#pragma unroll
        for (int c = 0; c < 64; ++c) {
            const float2 xa = *(const float2*)&Xs[c][n0];
            const float2 xb = *(const float2*)&Xs[c][n0 + 2];
            const float2 w  = *(const float2*)&Ws[c][oo0];
            acc[0][0] = fmaf(xa.x, w.x, acc[0][0]);
            acc[1][0] = fmaf(xa.y, w.x, acc[1][0]);
            acc[2][0] = fmaf(xb.x, w.x, acc[2][0]);
            acc[3][0] = fmaf(xb.y, w.x, acc[3][0]);
            acc[0][1] = fmaf(xa.x, w.y, acc[0][1]);
            acc[1][1] = fmaf(xa.y, w.y, acc[1][1]);
            acc[2][1] = fmaf(xb.x, w.y, acc[2][1]);
            acc[3][1] = fmaf(xb.y, w.y, acc[3][1]);
        }
    }

    // epilogue: transpose through LDS, then coalesced global write, layout [n][j][o]
    __syncthreads();
#pragma unroll
    for (int oi = 0; oi < 2; ++oi)
#pragma unroll
        for (int ni = 0; ni < 4; ++ni)
            Ys[oo0 + oi][n0 + ni] = acc[ni][oi];
    __syncthreads();
#pragma unroll
    for (int p = 0; p < 8; ++p) {
        const int e  = t + (p << 8);
        const int oo = e & 31;
        const int n  = e >> 5;
        Y[(size_t)(n * BRANCH + j) * OUT_DIM + o0 + oo] = Ys[oo][n];
    }
}

// Kernel B: pointwise dendritic decay + LIF + spike.
__global__ __launch_bounds__(256) void lif_pointwise(
    const float* __restrict__ Y,
    const float* __restrict__ mem,
    const float* __restrict__ spike,
    const float* __restrict__ d_input,
    const float* __restrict__ v_th,
    const float* __restrict__ b,
    const float* __restrict__ tau_m,
    const float* __restrict__ tau_n,
    float* __restrict__ out)
{
    const int idx = blockIdx.x * 256 + threadIdx.x;   // = n*OUT_DIM + o
    const int o   = idx & (OUT_DIM - 1);
    const int n   = idx >> 11;

    const float4 tn = ((const float4*)tau_n)[o];
    const float4 bb = ((const float4*)b)[o];
    const float4 di = ((const float4*)d_input)[idx];

    const size_t ybase = (size_t)(n * BRANCH) * OUT_DIM + o;
    const float y0 = Y[ybase];
    const float y1 = Y[ybase + OUT_DIM];
    const float y2 = Y[ybase + 2 * OUT_DIM];
    const float y3 = Y[ybase + 3 * OUT_DIM];

    float l = 0.0f;
    {
        const float bt = sigmoidf_(tn.x); l += bt * di.x + (1.0f - bt) * (y0 + bb.x);
    }
    {
        const float bt = sigmoidf_(tn.y); l += bt * di.y + (1.0f - bt) * (y1 + bb.y);
    }
    {
        const float bt = sigmoidf_(tn.z); l += bt * di.z + (1.0f - bt) * (y2 + bb.z);
    }
    {
        const float bt = sigmoidf_(tn.w); l += bt * di.w + (1.0f - bt) * (y3 + bb.w);
    }

    const float alpha = sigmoidf_(tau_m[o]);
    const float vt    = v_th[idx];
    const float m     = mem[idx] * alpha + (1.0f - alpha) * l - vt * spike[idx];

    out[idx] = m;
    out[BATCH * OUT_DIM + idx] = (m - vt) > 0.0f ? 1.0f : 0.0f;
}

extern "C" void kernel_launch(void* const* d_in, const int* in_sizes, int n_in,
                              void* d_out, int out_size, void* d_ws, size_t ws_size,
                              hipStream_t stream) {
    const float* X     = (const float*)d_in[0];  // input_spike [64][8192]
    const float* mem   = (const float*)d_in[1];  // [64][2048]
    const float* spike = (const float*)d_in[2];  // [64][2048]
    const float* dinp  = (const float*)d_in[3];  // [64][2048][4]
    const float* vth   = (const float*)d_in[4];  // [64][2048]
    const float* W     = (const float*)d_in[5];  // [8192][8192]
    const float* b     = (const float*)d_in[6];  // [8192]
    const float* tm    = (const float*)d_in[7];  // [2048]
    const float* tn    = (const float*)d_in[8];  // [2048][4]
    float* out = (float*)d_out;

    // workspace: Y [n][j][o] = 64*4*2048 floats = 2 MB
    float* Yw = (float*)d_ws;

    dend_gemm<<<256, 256, 0, stream>>>(X, W, Yw);
    lif_pointwise<<<(BATCH * OUT_DIM) / 256, 256, 0, stream>>>(
        Yw, mem, spike, dinp, vth, b, tm, tn, out);
}

// Round 2
// 31.738 us; speedup vs baseline: 2.6017x; 2.6017x over previous
//
#include <hip/hip_runtime.h>
#include <math.h>

#define BATCH   64
#define IN_DIM  8192
#define OUT_DIM 2048
#define BRANCH  4
#define CHUNK   2048
#define KT      128     // k per LDS tile
#define NT      16      // CHUNK / KT

typedef __attribute__((ext_vector_type(8))) short short8;   // 8 x bf16 (4 VGPR) MFMA operand
typedef __attribute__((ext_vector_type(4))) short short4v;  // 8-byte packed bf16x4
typedef __attribute__((ext_vector_type(4))) float f32x4;

__device__ __forceinline__ float sigmoidf_(float x) {
    return 1.0f / (1.0f + expf(-x));
}

// round-to-nearest-even fp32 -> bf16 bit pattern (low 16 bits of result)
__device__ __forceinline__ unsigned rne_bf16(float f) {
    unsigned u = __float_as_uint(f);
    return (u + 0x7fffu + ((u >> 16) & 1u)) >> 16;
}

// ---------------------------------------------------------------------------
// prep: X fp32 [64][8192] -> A-fragment-layout bf16 hi/lo streams.
// frag id = (j*4 + strip)*64 + kk ; lane l holds X[n = strip*16 + (l&15)]
//                                        [j*2048 + kk*32 + (l>>4)*8 + e], e=0..7
__global__ __launch_bounds__(256) void prep_x(const float* __restrict__ X,
                                              short8* __restrict__ Xfh,
                                              short8* __restrict__ Xfl) {
    const int gid = blockIdx.x * 256 + threadIdx.x;   // 65536 frag-lanes
    const int l  = gid & 63;
    const int kk = (gid >> 6) & 63;
    const int s  = (gid >> 12) & 3;
    const int j  = gid >> 14;
    const int n  = s * 16 + (l & 15);
    const int k0 = kk * 32 + ((l >> 4) << 3);
    const float* p = X + (size_t)n * IN_DIM + j * CHUNK + k0;
    const f32x4 a = *(const f32x4*)p;
    const f32x4 c = *(const f32x4*)(p + 4);
    float v[8] = {a[0], a[1], a[2], a[3], c[0], c[1], c[2], c[3]};
    short8 h, lo;
#pragma unroll
    for (int e = 0; e < 8; ++e) {
        unsigned hb = rne_bf16(v[e]);
        float fh = __uint_as_float(hb << 16);
        unsigned lb = rne_bf16(v[e] - fh);
        h[e]  = (short)hb;
        lo[e] = (short)lb;
    }
    Xfh[gid] = h;
    Xfl[gid] = lo;
}

// ---------------------------------------------------------------------------
// stage fp32 W regs -> split bf16 hi/lo in swizzled LDS
__device__ __forceinline__ void stage_store(char* Wh, char* Wl, const f32x4* wr,
                                            int wbyte0, int swz, int kq) {
#pragma unroll
    for (int i = 0; i < 4; ++i) {
        unsigned hb[4], lb[4];
#pragma unroll
        for (int e = 0; e < 4; ++e) {
            float f = wr[i][e];
            unsigned h = rne_bf16(f);
            float fh = __uint_as_float(h << 16);
            unsigned l = rne_bf16(f - fh);
            hb[e] = h; lb[e] = l;
        }
        short4v vh = { (short)hb[0], (short)hb[1], (short)hb[2], (short)hb[3] };
        short4v vl = { (short)lb[0], (short)lb[1], (short)lb[2], (short)lb[3] };
        const int kb   = (kq << 5) + (i << 3);     // byte offset of k within 256B row
        const int byte = wbyte0 + (kb ^ swz);
        *(short4v*)(Wh + byte) = vh;
        *(short4v*)(Wl + byte) = vl;
    }
}

// ---------------------------------------------------------------------------
// block-diagonal GEMM via bf16x3 MFMA emulation.
// grid: 256 = 64 o-tiles(32 wide) x 4 branches. block: 256 thr = 4 waves (n-strips).
__global__ __launch_bounds__(256) void dend_gemm(const short8* __restrict__ Xfh,
                                                 const short8* __restrict__ Xfl,
                                                 const float*  __restrict__ W,
                                                 float* __restrict__ Y) {
    __shared__ __align__(16) char WhL[2][32 * 256];   // 32 rows x 128 bf16 (256B), swizzled
    __shared__ __align__(16) char WlL[2][32 * 256];
    __shared__ float Ys[32][65];

    const int t    = threadIdx.x;
    const int bid  = blockIdx.x;
    const int j    = bid & 3;
    const int o0   = (bid >> 2) << 5;
    const int lane = t & 63;
    const int wv   = t >> 6;           // wave = n-strip 0..3

    // staging coords: 8 threads per W row, 16 fp32 each
    const int ri  = t >> 3;            // 0..31 (local o)
    const int kq  = t & 7;
    const float* wsrc = W + (size_t)((o0 + ri) * 4 + j) * IN_DIM + j * CHUNK + kq * 16;
    const int wbyte0 = ri << 8;
    const int swz    = (ri & 15) << 4;

    // A-fragment streams (L2-resident, coalesced 16B/lane)
    const short8* pAh = Xfh + (j * 4 + wv) * 4096 + lane;
    const short8* pAl = Xfl + (j * 4 + wv) * 4096 + lane;

    // B-frag read addressing
    const int o_l   = lane & 15;
    const int bswz  = o_l << 4;
    const int kgrp  = (lane >> 4) << 4;   // byte offset of k-group within step
    const int b0row = o_l << 8;
    const int b1row = (o_l + 16) << 8;

    f32x4 acc0 = {0.f, 0.f, 0.f, 0.f};
    f32x4 acc1 = {0.f, 0.f, 0.f, 0.f};

    f32x4  wr[4];
    short8 Ah0[4], Al0[4], Ah1[4], Al1[4];

    // ---- prologue ----
#pragma unroll
    for (int i = 0; i < 4; ++i)
        wr[i] = *(const f32x4*)(wsrc + i * 4);
    stage_store(WhL[0], WlL[0], wr, wbyte0, swz, kq);
#pragma unroll
    for (int i = 0; i < 4; ++i)
        wr[i] = *(const f32x4*)(wsrc + KT + i * 4);
#pragma unroll
    for (int i = 0; i < 4; ++i) { Ah0[i] = pAh[i * 64];       Al0[i] = pAl[i * 64]; }
#pragma unroll
    for (int i = 0; i < 4; ++i) { Ah1[i] = pAh[(4 + i) * 64]; Al1[i] = pAl[(4 + i) * 64]; }
    __syncthreads();

#define BODY(kt, AH, AL)                                                            \
  {                                                                                 \
    if ((kt) + 1 < NT)                                                              \
        stage_store(WhL[((kt) + 1) & 1], WlL[((kt) + 1) & 1], wr, wbyte0, swz, kq); \
    if ((kt) + 2 < NT) {                                                            \
        _Pragma("unroll")                                                           \
        for (int i = 0; i < 4; ++i)                                                 \
            wr[i] = *(const f32x4*)(wsrc + ((kt) + 2) * KT + i * 4);                \
    }                                                                               \
    _Pragma("unroll")                                                               \
    for (int st = 0; st < 4; ++st) {                                                \
        const int off = ((st << 6) + kgrp) ^ bswz;                                  \
        short8 bh0 = *(const short8*)(&WhL[(kt) & 1][b0row + off]);                 \
        short8 bl0 = *(const short8*)(&WlL[(kt) & 1][b0row + off]);                 \
        short8 bh1 = *(const short8*)(&WhL[(kt) & 1][b1row + off]);                 \
        short8 bl1 = *(const short8*)(&WlL[(kt) & 1][b1row + off]);                 \
        acc0 = __builtin_amdgcn_mfma_f32_16x16x32_bf16(AH[st], bh0, acc0, 0, 0, 0); \
        acc1 = __builtin_amdgcn_mfma_f32_16x16x32_bf16(AH[st], bh1, acc1, 0, 0, 0); \
        acc0 = __builtin_amdgcn_mfma_f32_16x16x32_bf16(AL[st], bh0, acc0, 0, 0, 0); \
        acc1 = __builtin_amdgcn_mfma_f32_16x16x32_bf16(AL[st], bh1, acc1, 0, 0, 0); \
        acc0 = __builtin_amdgcn_mfma_f32_16x16x32_bf16(AH[st], bl0, acc0, 0, 0, 0); \
        acc1 = __builtin_amdgcn_mfma_f32_16x16x32_bf16(AH[st], bl1, acc1, 0, 0, 0); \
    }                                                                               \
    if ((kt) + 2 < NT) {                                                            \
        _Pragma("unroll")                                                           \
        for (int i = 0; i < 4; ++i) {                                               \
            AH[i] = pAh[(((kt) + 2) * 4 + i) * 64];                                 \
            AL[i] = pAl[(((kt) + 2) * 4 + i) * 64];                                 \
        }                                                                           \
    }                                                                               \
    __syncthreads();                                                                \
  }

#pragma unroll 1
    for (int kt = 0; kt < NT; kt += 2) {
        BODY(kt,     Ah0, Al0)
        BODY(kt + 1, Ah1, Al1)
    }
#undef BODY

    // ---- epilogue: frag -> LDS transpose -> coalesced Y write, layout [n][j][o]
    {
        const int rb = (wv << 4) + ((lane >> 4) << 2);   // D row = (lane>>4)*4 + r
#pragma unroll
        for (int r = 0; r < 4; ++r) {
            Ys[o_l][rb + r]      = acc0[r];
            Ys[o_l + 16][rb + r] = acc1[r];
        }
    }
    __syncthreads();
#pragma unroll
    for (int p = 0; p < 8; ++p) {
        const int e  = t + (p << 8);
        const int oo = e & 31;
        const int n  = e >> 5;
        Y[(size_t)((n << 2) + j) * OUT_DIM + o0 + oo] = Ys[oo][n];
    }
}

// ---------------------------------------------------------------------------
// pointwise dendritic decay + LIF + spike
__global__ __launch_bounds__(256) void lif_pointwise(
    const float* __restrict__ Y,
    const float* __restrict__ mem,
    const float* __restrict__ spike,
    const float* __restrict__ d_input,
    const float* __restrict__ v_th,
    const float* __restrict__ b,
    const float* __restrict__ tau_m,
    const float* __restrict__ tau_n,
    float* __restrict__ out)
{
    const int idx = blockIdx.x * 256 + threadIdx.x;   // = n*OUT_DIM + o
    const int o   = idx & (OUT_DIM - 1);
    const int n   = idx >> 11;

    const float4 tn = ((const float4*)tau_n)[o];
    const float4 bb = ((const float4*)b)[o];
    const float4 di = ((const float4*)d_input)[idx];

    const size_t ybase = (size_t)(n * BRANCH) * OUT_DIM + o;
    const float y0 = Y[ybase];
    const float y1 = Y[ybase + OUT_DIM];
    const float y2 = Y[ybase + 2 * OUT_DIM];
    const float y3 = Y[ybase + 3 * OUT_DIM];

    float l = 0.0f;
    { const float bt = sigmoidf_(tn.x); l += bt * di.x + (1.0f - bt) * (y0 + bb.x); }
    { const float bt = sigmoidf_(tn.y); l += bt * di.y + (1.0f - bt) * (y1 + bb.y); }
    { const float bt = sigmoidf_(tn.z); l += bt * di.z + (1.0f - bt) * (y2 + bb.z); }
    { const float bt = sigmoidf_(tn.w); l += bt * di.w + (1.0f - bt) * (y3 + bb.w); }

    const float alpha = sigmoidf_(tau_m[o]);
    const float vt    = v_th[idx];
    const float m     = mem[idx] * alpha + (1.0f - alpha) * l - vt * spike[idx];

    out[idx] = m;
    out[BATCH * OUT_DIM + idx] = (m - vt) > 0.0f ? 1.0f : 0.0f;
}

extern "C" void kernel_launch(void* const* d_in, const int* in_sizes, int n_in,
                              void* d_out, int out_size, void* d_ws, size_t ws_size,
                              hipStream_t stream) {
    const float* X     = (const float*)d_in[0];
    const float* mem   = (const float*)d_in[1];
    const float* spike = (const float*)d_in[2];
    const float* dinp  = (const float*)d_in[3];
    const float* vth   = (const float*)d_in[4];
    const float* W     = (const float*)d_in[5];
    const float* b     = (const float*)d_in[6];
    const float* tm    = (const float*)d_in[7];
    const float* tn    = (const float*)d_in[8];
    float* out = (float*)d_out;

    // workspace layout: Xfh (1 MB) | Xfl (1 MB) | Y (2 MB)
    short8* Xfh = (short8*)d_ws;
    short8* Xfl = (short8*)((char*)d_ws + (1u << 20));
    float*  Yw  = (float*)((char*)d_ws + (2u << 20));

    prep_x<<<256, 256, 0, stream>>>(X, Xfh, Xfl);
    dend_gemm<<<256, 256, 0, stream>>>(Xfh, Xfl, W, Yw);
    lif_pointwise<<<512, 256, 0, stream>>>(Yw, mem, spike, dinp, vth, b, tm, tn, out);
}